// Round 19
// baseline (118.405 us; speedup 1.0000x reference)
//
#include <hip/hip_runtime.h>
#include <hip/hip_bf16.h>
#include <math.h>

#define B_ 4
#define S_ 2048
#define NH_ 16
#define DH_ 64
#define DM_ 1024

typedef __attribute__((ext_vector_type(4))) float f32x4;
typedef __attribute__((ext_vector_type(8))) short s16x8;
typedef __attribute__((ext_vector_type(2))) unsigned u32x2;

// native exp2 via device-libs (lowers to v_exp_f32, compiler-managed hazards)
extern "C" __device__ float __ocml_native_exp2_f32(float);
static __device__ __forceinline__ float nexp2(float x) {
  return __ocml_native_exp2_f32(x);
}

static __device__ __forceinline__ short f2bf(float f) {
  union { float f; unsigned u; } c; c.f = f;
  unsigned r = c.u + 0x7fffu + ((c.u >> 16) & 1u);
  return (short)(r >> 16);
}

// single-instruction packed f32->bf16 (RNE), lo = a, hi = b (HW-proven)
static __device__ __forceinline__ unsigned pkbf_fast(float a, float b) {
  unsigned r;
  asm("v_cvt_pk_bf16_f32 %0, %1, %2" : "=v"(r) : "v"(a), "v"(b));
  return r;
}

static __device__ __forceinline__ void gload16(const void* g, void* l) {
  __builtin_amdgcn_global_load_lds(
      (const __attribute__((address_space(1))) void*)g,
      (__attribute__((address_space(3))) void*)l, 16, 0, 0);
}

// ---------- fp32 -> bf16 convert ----------
__global__ void cvt_kernel(const float* __restrict__ in, short* __restrict__ out) {
  int i = (blockIdx.x * 256 + threadIdx.x) * 8;
  f32x4 a = *(const f32x4*)(in + i);
  f32x4 b = *(const f32x4*)(in + i + 4);
  s16x8 o;
  o[0] = f2bf(a[0]); o[1] = f2bf(a[1]); o[2] = f2bf(a[2]); o[3] = f2bf(a[3]);
  o[4] = f2bf(b[0]); o[5] = f2bf(b[1]); o[6] = f2bf(b[2]); o[7] = f2bf(b[3]);
  *(s16x8*)(out + i) = o;
}

// ---------- transpose+convert both W's in one launch (z selects) ----------
__global__ void tcvt_kernel(const float* __restrict__ W0, const float* __restrict__ W1,
                            short* __restrict__ T0, short* __restrict__ T1) {
  __shared__ float t[32][33];
  const float* W = blockIdx.z ? W1 : W0;
  short* WT = blockIdx.z ? T1 : T0;
  int tx = threadIdx.x & 31, ty = threadIdx.x >> 5;
  int bn = blockIdx.x * 32, bk = blockIdx.y * 32;
#pragma unroll
  for (int r = 0; r < 32; r += 8)
    t[ty + r][tx] = W[(size_t)(bk + ty + r) * DM_ + bn + tx];
  __syncthreads();
#pragma unroll
  for (int r = 0; r < 32; r += 8)
    WT[(size_t)(bn + ty + r) * DM_ + bk + tx] = f2bf(t[tx][ty + r]);
}

// ---------- bf16 GEMM: 128x128 tiles (proven), grid (8,64).
// EPI0: write Q [bh][s][d] and Q^T [bh][d][s], pre-scaled by sqrt(C).
// EPI1: bias add, fp32 out. ----------
template <int EPI>
__global__ __launch_bounds__(256, 2) void gemm_kernel(
    const short* __restrict__ A, const short* __restrict__ BT,
    void* __restrict__ Cout, short* __restrict__ CoutT,
    const float* __restrict__ bias) {
  __shared__ short Al[128 * 64];
  __shared__ short Bl[128 * 64];
  const int tid = threadIdx.x;
  const int wid = tid >> 6, lane = tid & 63;
  const int l15 = lane & 15, l4 = lane >> 4;
  const int bm = blockIdx.y * 128, bn = blockIdx.x * 128;
  const int wm = (wid >> 1) * 64, wn = (wid & 1) * 64;
  f32x4 acc[4][4] = {};

  for (int kt = 0; kt < DM_; kt += 64) {
    __syncthreads();
#pragma unroll
    for (int j = 0; j < 4; ++j) {
      int s = j * 256 + tid;
      int row = s >> 3;
      int sl = (s & 7) ^ (row & 7);
      gload16(A + (size_t)(bm + row) * DM_ + kt + sl * 8, &Al[j * 2048 + wid * 512]);
    }
#pragma unroll
    for (int j = 0; j < 4; ++j) {
      int s = j * 256 + tid;
      int row = s >> 3;
      int sl = (s & 7) ^ (row & 7);
      gload16(BT + (size_t)(bn + row) * DM_ + kt + sl * 8, &Bl[j * 2048 + wid * 512]);
    }
    __syncthreads();
#pragma unroll
    for (int kk = 0; kk < 2; ++kk) {
      s16x8 af[4], bfr[4];
#pragma unroll
      for (int mi = 0; mi < 4; ++mi) {
        int row = wm + mi * 16 + l15;
        int sl = (kk * 4 + l4) ^ (row & 7);
        af[mi] = *(const s16x8*)&Al[row * 64 + sl * 8];
      }
#pragma unroll
      for (int ni = 0; ni < 4; ++ni) {
        int row = wn + ni * 16 + l15;
        int sl = (kk * 4 + l4) ^ (row & 7);
        bfr[ni] = *(const s16x8*)&Bl[row * 64 + sl * 8];
      }
#pragma unroll
      for (int mi = 0; mi < 4; ++mi)
#pragma unroll
        for (int ni = 0; ni < 4; ++ni)
          acc[mi][ni] = __builtin_amdgcn_mfma_f32_16x16x32_bf16(af[mi], bfr[ni], acc[mi][ni], 0, 0, 0);
    }
  }

  if (EPI == 0) {
    const float sc = 0.42466089786f;     // sqrt(0.125 * log2 e)
    short* Q = (short*)Cout;
#pragma unroll
    for (int mi = 0; mi < 4; ++mi)
#pragma unroll
      for (int ni = 0; ni < 4; ++ni) {
        int rr0 = bm + wm + mi * 16 + l4 * 4;
        int cc = bn + wn + ni * 16 + l15;
        int b = rr0 >> 11, s0 = rr0 & 2047, h = cc >> 6, d = cc & 63;
        int bh = b * NH_ + h;
        u32x2 pk;
        pk[0] = pkbf_fast(acc[mi][ni][0] * sc, acc[mi][ni][1] * sc);
        pk[1] = pkbf_fast(acc[mi][ni][2] * sc, acc[mi][ni][3] * sc);
        Q[(((size_t)bh * S_ + s0 + 0) << 6) + d] = (short)(pk[0] & 0xffff);
        Q[(((size_t)bh * S_ + s0 + 1) << 6) + d] = (short)(pk[0] >> 16);
        Q[(((size_t)bh * S_ + s0 + 2) << 6) + d] = (short)(pk[1] & 0xffff);
        Q[(((size_t)bh * S_ + s0 + 3) << 6) + d] = (short)(pk[1] >> 16);
        *(u32x2*)&CoutT[(((size_t)bh * DH_ + d) << 11) + s0] = pk;
      }
  } else {
    float* O = (float*)Cout;
#pragma unroll
    for (int mi = 0; mi < 4; ++mi)
#pragma unroll
      for (int ni = 0; ni < 4; ++ni)
#pragma unroll
        for (int r = 0; r < 4; ++r) {
          int rr = bm + wm + mi * 16 + l4 * 4 + r;
          int cc = bn + wn + ni * 16 + l15;
          O[(size_t)rr * DM_ + cc] = acc[mi][ni][r] + bias[cc];
        }
  }
}

// ---------- causal flash attention, Q=K=V (inputs pre-scaled by sqrt(C)) ----
// PV and l use K=32 MFMA (16x16x16 costs the SAME cycles as 16x16x32 on
// CDNA4). P re-laid-out for the K=32 B-operand via a 2KB wave-private LDS
// round-trip (XOR-swizzled). Shift-free softmax; exp2 native; cvt_pk packing.
__global__ __launch_bounds__(256, 4) void attn_kernel(
    const short* __restrict__ Qb, const short* __restrict__ QbT,
    short* __restrict__ Ctx) {
  __shared__ short Kl[2][64 * 64];
  __shared__ short Vt[2][64 * 64];
  __shared__ short Pl[4][16 * 64];        // per-wave P buffer (per-qi reuse)
  const int tid = threadIdx.x;
  const int wid = tid >> 6, lane = tid & 63;
  const int l15 = lane & 15, l4 = lane >> 4;
  const int bid = blockIdx.x;
  const int bh = bid & 63;
  const int g = bid >> 6;
  const int qt = (int)((0x32104567ba98cdefULL >> (g * 4)) & 15);
  const short* Qh = Qb + (size_t)bh * S_ * DH_;
  const short* QTh = QbT + (size_t)bh * DH_ * S_;
  const int q0 = qt * 128 + wid * 32;

  s16x8 aq[2][2];
#pragma unroll
  for (int qi = 0; qi < 2; ++qi)
#pragma unroll
    for (int kk = 0; kk < 2; ++kk)
      aq[qi][kk] = *(const s16x8*)(Qh + (size_t)(q0 + qi * 16 + l15) * DH_ + kk * 32 + l4 * 8);

  f32x4 acc_o[4][2] = {};
  f32x4 lacc[2] = {};
  s16x8 ones8;
#pragma unroll
  for (int i = 0; i < 8; ++i) ones8[i] = (short)0x3F80;

  // hoisted LDS offsets (short units)
  const int e7 = l15 & 7;
  const int ka0 = l15 * 64 + ((l4) ^ e7) * 8;
  const int ka1 = l15 * 64 + ((4 + l4) ^ e7) * 8;
  // V^T K=32 A-frag read: octet 4*blk + l4, row df*16+l15 (df*1024 folded)
  const int vro0 = l15 * 64 + ((l4) ^ e7) * 8;        // blk 0
  const int vro1 = l15 * 64 + ((4 + l4) ^ e7) * 8;    // blk 1
  // P write (b64): octet 2ki+(l4>>1), half l4&1
  int pwo[4];
#pragma unroll
  for (int ki = 0; ki < 4; ++ki)
    pwo[ki] = l15 * 64 + (((2 * ki + (l4 >> 1)) ^ e7) << 3) + (l4 & 1) * 4;
  // P read (b128): octet 4*blk + l4 (same swizzle as write)
  const int pro0 = vro0, pro1 = vro1;

  const int c0 = wid * 64 + lane, c1 = c0 + 256;
  const int r0 = c0 >> 3, s0 = (c0 & 7) ^ (r0 & 7);
  const int r1 = c1 >> 3, s1 = (c1 & 7) ^ (r1 & 7);
  const short* pK0 = Qh + r0 * 64 + s0 * 8;
  const short* pK1 = Qh + r1 * 64 + s1 * 8;
  const short* pV0 = QTh + (size_t)r0 * S_ + s0 * 8;
  const short* pV1 = QTh + (size_t)r1 * S_ + s1 * 8;

  auto stage = [&](int buf) {
    gload16(pK0, &Kl[buf][wid * 512]);
    gload16(pK1, &Kl[buf][wid * 512 + 2048]);
    gload16(pV0, &Vt[buf][wid * 512]);
    gload16(pV1, &Vt[buf][wid * 512 + 2048]);
    pK0 += 4096; pK1 += 4096;
    pV0 += 64;   pV1 += 64;
  };

  stage(0);

  int cur = 0;
  const int nt = qt * 2 + 2;
  for (int t = 0; t < nt; ++t) {
    asm volatile("s_waitcnt vmcnt(0)" ::: "memory");
    __syncthreads();
    if (t + 1 < nt) stage(cur ^ 1);
    const int kv0 = t * 64;

    if (kv0 <= q0) {
      const short* kl = &Kl[cur][0];
      const short* vt = &Vt[cur][0];
      short* Pw = &Pl[wid][0];
      // S^T = mfma32(K rows, Q rows)
      f32x4 sa[4][2] = {};
      __builtin_amdgcn_s_setprio(1);
#pragma unroll
      for (int kk = 0; kk < 2; ++kk) {
        const int kb = (kk == 0) ? ka0 : ka1;
        s16x8 ka[4];
#pragma unroll
        for (int ki = 0; ki < 4; ++ki)
          ka[ki] = *(const s16x8*)&kl[kb + ki * 1024];
#pragma unroll
        for (int ki = 0; ki < 4; ++ki)
#pragma unroll
          for (int qi = 0; qi < 2; ++qi)
            sa[ki][qi] = __builtin_amdgcn_mfma_f32_16x16x32_bf16(ka[ki], aq[qi][kk], sa[ki][qi], 0, 0, 0);
      }
      __builtin_amdgcn_s_setprio(0);
      if (kv0 + 63 > q0) {                // boundary: causal mask
#pragma unroll
        for (int ki = 0; ki < 4; ++ki)
#pragma unroll
          for (int qi = 0; qi < 2; ++qi)
#pragma unroll
            for (int r = 0; r < 4; ++r) {
              int kvg = kv0 + ki * 16 + l4 * 4 + r;
              int qg = q0 + qi * 16 + l15;
              if (kvg > qg) sa[ki][qi][r] = -INFINITY;
            }
      }
      // P = exp2(S'), packed bf16 pairs
      unsigned pw[4][2][2];
#pragma unroll
      for (int ki = 0; ki < 4; ++ki)
#pragma unroll
        for (int qi = 0; qi < 2; ++qi) {
          float e0 = nexp2(sa[ki][qi][0]);
          float e1 = nexp2(sa[ki][qi][1]);
          float e2 = nexp2(sa[ki][qi][2]);
          float e3 = nexp2(sa[ki][qi][3]);
          pw[ki][qi][0] = pkbf_fast(e0, e1);
          pw[ki][qi][1] = pkbf_fast(e2, e3);
        }
      // per-qi: P round-trip to K=32 layout, then l + PV on mfma32
      __builtin_amdgcn_s_setprio(1);
#pragma unroll
      for (int qi = 0; qi < 2; ++qi) {
#pragma unroll
        for (int ki = 0; ki < 4; ++ki) {
          u32x2 w; w[0] = pw[ki][qi][0]; w[1] = pw[ki][qi][1];
          *(u32x2*)&Pw[pwo[ki]] = w;
        }
        s16x8 pb0 = *(const s16x8*)&Pw[pro0];
        s16x8 pb1 = *(const s16x8*)&Pw[pro1];
        lacc[qi] = __builtin_amdgcn_mfma_f32_16x16x32_bf16(ones8, pb0, lacc[qi], 0, 0, 0);
        lacc[qi] = __builtin_amdgcn_mfma_f32_16x16x32_bf16(ones8, pb1, lacc[qi], 0, 0, 0);
#pragma unroll
        for (int df = 0; df < 4; ++df) {
          s16x8 av0 = *(const s16x8*)&vt[df * 1024 + vro0];
          s16x8 av1 = *(const s16x8*)&vt[df * 1024 + vro1];
          acc_o[df][qi] = __builtin_amdgcn_mfma_f32_16x16x32_bf16(av0, pb0, acc_o[df][qi], 0, 0, 0);
          acc_o[df][qi] = __builtin_amdgcn_mfma_f32_16x16x32_bf16(av1, pb1, acc_o[df][qi], 0, 0, 0);
        }
      }
      __builtin_amdgcn_s_setprio(0);
    }
    cur ^= 1;
  }

  const int b = bh >> 4, h = bh & 15;
  const float ISQC = 2.35482208f;         // 1 / sqrt(0.125 * log2 e)
  float inv[2] = {ISQC / lacc[0][0], ISQC / lacc[1][0]};
#pragma unroll
  for (int df = 0; df < 4; ++df)
#pragma unroll
    for (int qi = 0; qi < 2; ++qi) {
      int qg = q0 + qi * 16 + l15;
      int col = h * 64 + df * 16 + l4 * 4;
      u32x2 pk;
      pk[0] = pkbf_fast(acc_o[df][qi][0] * inv[qi], acc_o[df][qi][1] * inv[qi]);
      pk[1] = pkbf_fast(acc_o[df][qi][2] * inv[qi], acc_o[df][qi][3] * inv[qi]);
      *(u32x2*)&Ctx[(size_t)(b * S_ + qg) * DM_ + col] = pk;
    }
}

extern "C" void kernel_launch(void* const* d_in, const int* in_sizes, int n_in,
                              void* d_out, int out_size, void* d_ws, size_t ws_size,
                              hipStream_t stream) {
  const float* x  = (const float*)d_in[0];
  const float* Wq = (const float*)d_in[1];
  const float* Wo = (const float*)d_in[2];
  const float* bo = (const float*)d_in[3];
  float* out = (float*)d_out;
  char* ws = (char*)d_ws;

  short* xb  = (short*)(ws);                 // 16 MB (x bf16, reused as ctx)
  short* WqT = (short*)(ws + 16777216);      //  2 MB
  short* WoT = (short*)(ws + 18874368);      //  2 MB
  short* Qb  = (short*)(ws + 20971520);      // 16 MB  [bh][s][d], *sqrt(C)
  short* QbT = (short*)(ws + 37748736);      // 16 MB  [bh][d][s], *sqrt(C)
  short* Ctx = xb;  // alias: x dead after GEMM1

  cvt_kernel<<<4096, 256, 0, stream>>>(x, xb);
  tcvt_kernel<<<dim3(32, 32, 2), 256, 0, stream>>>(Wq, Wo, WqT, WoT);
  gemm_kernel<0><<<dim3(8, 64), 256, 0, stream>>>(xb, WqT, Qb, QbT, nullptr);
  attn_kernel<<<1024, 256, 0, stream>>>(Qb, QbT, Ctx);
  gemm_kernel<1><<<dim3(8, 64), 256, 0, stream>>>(Ctx, WoT, out, nullptr, bo);
}

// Round 20
// 118.146 us; speedup vs baseline: 1.0022x; 1.0022x over previous
//
#include <hip/hip_runtime.h>
#include <hip/hip_bf16.h>
#include <math.h>

#define B_ 4
#define S_ 2048
#define NH_ 16
#define DH_ 64
#define DM_ 1024

typedef __attribute__((ext_vector_type(4))) float f32x4;
typedef __attribute__((ext_vector_type(8))) short s16x8;
typedef __attribute__((ext_vector_type(2))) unsigned u32x2;

// native exp2 via device-libs (lowers to v_exp_f32, compiler-managed hazards)
extern "C" __device__ float __ocml_native_exp2_f32(float);
static __device__ __forceinline__ float nexp2(float x) {
  return __ocml_native_exp2_f32(x);
}

static __device__ __forceinline__ short f2bf(float f) {
  union { float f; unsigned u; } c; c.f = f;
  unsigned r = c.u + 0x7fffu + ((c.u >> 16) & 1u);
  return (short)(r >> 16);
}

// single-instruction packed f32->bf16 (RNE), lo = a, hi = b (HW-proven)
static __device__ __forceinline__ unsigned pkbf_fast(float a, float b) {
  unsigned r;
  asm("v_cvt_pk_bf16_f32 %0, %1, %2" : "=v"(r) : "v"(a), "v"(b));
  return r;
}

static __device__ __forceinline__ void gload16(const void* g, void* l) {
  __builtin_amdgcn_global_load_lds(
      (const __attribute__((address_space(1))) void*)g,
      (__attribute__((address_space(3))) void*)l, 16, 0, 0);
}

// ---------- fp32 -> bf16 convert ----------
__global__ void cvt_kernel(const float* __restrict__ in, short* __restrict__ out) {
  int i = (blockIdx.x * 256 + threadIdx.x) * 8;
  f32x4 a = *(const f32x4*)(in + i);
  f32x4 b = *(const f32x4*)(in + i + 4);
  s16x8 o;
  o[0] = f2bf(a[0]); o[1] = f2bf(a[1]); o[2] = f2bf(a[2]); o[3] = f2bf(a[3]);
  o[4] = f2bf(b[0]); o[5] = f2bf(b[1]); o[6] = f2bf(b[2]); o[7] = f2bf(b[3]);
  *(s16x8*)(out + i) = o;
}

// ---------- transpose+convert both W's in one launch (z selects) ----------
__global__ void tcvt_kernel(const float* __restrict__ W0, const float* __restrict__ W1,
                            short* __restrict__ T0, short* __restrict__ T1) {
  __shared__ float t[32][33];
  const float* W = blockIdx.z ? W1 : W0;
  short* WT = blockIdx.z ? T1 : T0;
  int tx = threadIdx.x & 31, ty = threadIdx.x >> 5;
  int bn = blockIdx.x * 32, bk = blockIdx.y * 32;
#pragma unroll
  for (int r = 0; r < 32; r += 8)
    t[ty + r][tx] = W[(size_t)(bk + ty + r) * DM_ + bn + tx];
  __syncthreads();
#pragma unroll
  for (int r = 0; r < 32; r += 8)
    WT[(size_t)(bn + ty + r) * DM_ + bk + tx] = f2bf(t[tx][ty + r]);
}

// ---------- bf16 GEMM: 128x128 tiles (proven), grid (8,64).
// EPI0: write Q [bh][s][d] and Q^T [bh][d][s], pre-scaled by sqrt(C).
// EPI1: bias add, fp32 out. ----------
template <int EPI>
__global__ __launch_bounds__(256, 2) void gemm_kernel(
    const short* __restrict__ A, const short* __restrict__ BT,
    void* __restrict__ Cout, short* __restrict__ CoutT,
    const float* __restrict__ bias) {
  __shared__ short Al[128 * 64];
  __shared__ short Bl[128 * 64];
  const int tid = threadIdx.x;
  const int wid = tid >> 6, lane = tid & 63;
  const int l15 = lane & 15, l4 = lane >> 4;
  const int bm = blockIdx.y * 128, bn = blockIdx.x * 128;
  const int wm = (wid >> 1) * 64, wn = (wid & 1) * 64;
  f32x4 acc[4][4] = {};

  for (int kt = 0; kt < DM_; kt += 64) {
    __syncthreads();
#pragma unroll
    for (int j = 0; j < 4; ++j) {
      int s = j * 256 + tid;
      int row = s >> 3;
      int sl = (s & 7) ^ (row & 7);
      gload16(A + (size_t)(bm + row) * DM_ + kt + sl * 8, &Al[j * 2048 + wid * 512]);
    }
#pragma unroll
    for (int j = 0; j < 4; ++j) {
      int s = j * 256 + tid;
      int row = s >> 3;
      int sl = (s & 7) ^ (row & 7);
      gload16(BT + (size_t)(bn + row) * DM_ + kt + sl * 8, &Bl[j * 2048 + wid * 512]);
    }
    __syncthreads();
#pragma unroll
    for (int kk = 0; kk < 2; ++kk) {
      s16x8 af[4], bfr[4];
#pragma unroll
      for (int mi = 0; mi < 4; ++mi) {
        int row = wm + mi * 16 + l15;
        int sl = (kk * 4 + l4) ^ (row & 7);
        af[mi] = *(const s16x8*)&Al[row * 64 + sl * 8];
      }
#pragma unroll
      for (int ni = 0; ni < 4; ++ni) {
        int row = wn + ni * 16 + l15;
        int sl = (kk * 4 + l4) ^ (row & 7);
        bfr[ni] = *(const s16x8*)&Bl[row * 64 + sl * 8];
      }
#pragma unroll
      for (int mi = 0; mi < 4; ++mi)
#pragma unroll
        for (int ni = 0; ni < 4; ++ni)
          acc[mi][ni] = __builtin_amdgcn_mfma_f32_16x16x32_bf16(af[mi], bfr[ni], acc[mi][ni], 0, 0, 0);
    }
  }

  if (EPI == 0) {
    const float sc = 0.42466089786f;     // sqrt(0.125 * log2 e)
    short* Q = (short*)Cout;
#pragma unroll
    for (int mi = 0; mi < 4; ++mi)
#pragma unroll
      for (int ni = 0; ni < 4; ++ni) {
        int rr0 = bm + wm + mi * 16 + l4 * 4;
        int cc = bn + wn + ni * 16 + l15;
        int b = rr0 >> 11, s0 = rr0 & 2047, h = cc >> 6, d = cc & 63;
        int bh = b * NH_ + h;
        u32x2 pk;
        pk[0] = pkbf_fast(acc[mi][ni][0] * sc, acc[mi][ni][1] * sc);
        pk[1] = pkbf_fast(acc[mi][ni][2] * sc, acc[mi][ni][3] * sc);
        Q[(((size_t)bh * S_ + s0 + 0) << 6) + d] = (short)(pk[0] & 0xffff);
        Q[(((size_t)bh * S_ + s0 + 1) << 6) + d] = (short)(pk[0] >> 16);
        Q[(((size_t)bh * S_ + s0 + 2) << 6) + d] = (short)(pk[1] & 0xffff);
        Q[(((size_t)bh * S_ + s0 + 3) << 6) + d] = (short)(pk[1] >> 16);
        *(u32x2*)&CoutT[(((size_t)bh * DH_ + d) << 11) + s0] = pk;
      }
  } else {
    float* O = (float*)Cout;
#pragma unroll
    for (int mi = 0; mi < 4; ++mi)
#pragma unroll
      for (int ni = 0; ni < 4; ++ni)
#pragma unroll
        for (int r = 0; r < 4; ++r) {
          int rr = bm + wm + mi * 16 + l4 * 4 + r;
          int cc = bn + wn + ni * 16 + l15;
          O[(size_t)rr * DM_ + cc] = acc[mi][ni][r] + bias[cc];
        }
  }
}

// ---------- causal flash attention, Q=K=V (inputs pre-scaled by sqrt(C)) ----
// PV and l use K=32 MFMA (16x16x16 costs the SAME cycles as 16x16x32 on
// CDNA4). P re-laid-out for the K=32 B-operand via a 2KB wave-private LDS
// round-trip (XOR-swizzled). Shift-free softmax; exp2 native; cvt_pk packing.
__global__ __launch_bounds__(256, 4) void attn_kernel(
    const short* __restrict__ Qb, const short* __restrict__ QbT,
    short* __restrict__ Ctx) {
  __shared__ short Kl[2][64 * 64];
  __shared__ short Vt[2][64 * 64];
  __shared__ short Pl[4][16 * 64];        // per-wave P buffer (per-qi reuse)
  const int tid = threadIdx.x;
  const int wid = tid >> 6, lane = tid & 63;
  const int l15 = lane & 15, l4 = lane >> 4;
  const int bid = blockIdx.x;
  const int bh = bid & 63;
  const int g = bid >> 6;
  const int qt = (int)((0x32104567ba98cdefULL >> (g * 4)) & 15);
  const short* Qh = Qb + (size_t)bh * S_ * DH_;
  const short* QTh = QbT + (size_t)bh * DH_ * S_;
  const int q0 = qt * 128 + wid * 32;

  s16x8 aq[2][2];
#pragma unroll
  for (int qi = 0; qi < 2; ++qi)
#pragma unroll
    for (int kk = 0; kk < 2; ++kk)
      aq[qi][kk] = *(const s16x8*)(Qh + (size_t)(q0 + qi * 16 + l15) * DH_ + kk * 32 + l4 * 8);

  f32x4 acc_o[4][2] = {};
  f32x4 lacc[2] = {};
  s16x8 ones8;
#pragma unroll
  for (int i = 0; i < 8; ++i) ones8[i] = (short)0x3F80;

  // hoisted LDS offsets (short units)
  const int e7 = l15 & 7;
  const int ka0 = l15 * 64 + ((l4) ^ e7) * 8;
  const int ka1 = l15 * 64 + ((4 + l4) ^ e7) * 8;
  // V^T K=32 A-frag read: octet 4*blk + l4, row df*16+l15 (df*1024 folded)
  const int vro0 = l15 * 64 + ((l4) ^ e7) * 8;        // blk 0
  const int vro1 = l15 * 64 + ((4 + l4) ^ e7) * 8;    // blk 1
  // P write (b64): octet 2ki+(l4>>1), half l4&1
  int pwo[4];
#pragma unroll
  for (int ki = 0; ki < 4; ++ki)
    pwo[ki] = l15 * 64 + (((2 * ki + (l4 >> 1)) ^ e7) << 3) + (l4 & 1) * 4;
  // P read (b128): octet 4*blk + l4 (same swizzle as write)
  const int pro0 = vro0, pro1 = vro1;

  const int c0 = wid * 64 + lane, c1 = c0 + 256;
  const int r0 = c0 >> 3, s0 = (c0 & 7) ^ (r0 & 7);
  const int r1 = c1 >> 3, s1 = (c1 & 7) ^ (r1 & 7);
  const short* pK0 = Qh + r0 * 64 + s0 * 8;
  const short* pK1 = Qh + r1 * 64 + s1 * 8;
  const short* pV0 = QTh + (size_t)r0 * S_ + s0 * 8;
  const short* pV1 = QTh + (size_t)r1 * S_ + s1 * 8;

  auto stage = [&](int buf) {
    gload16(pK0, &Kl[buf][wid * 512]);
    gload16(pK1, &Kl[buf][wid * 512 + 2048]);
    gload16(pV0, &Vt[buf][wid * 512]);
    gload16(pV1, &Vt[buf][wid * 512 + 2048]);
    pK0 += 4096; pK1 += 4096;
    pV0 += 64;   pV1 += 64;
  };

  stage(0);

  int cur = 0;
  const int nt = qt * 2 + 2;
  for (int t = 0; t < nt; ++t) {
    asm volatile("s_waitcnt vmcnt(0)" ::: "memory");
    __syncthreads();
    if (t + 1 < nt) stage(cur ^ 1);
    const int kv0 = t * 64;

    if (kv0 <= q0) {
      const short* kl = &Kl[cur][0];
      const short* vt = &Vt[cur][0];
      short* Pw = &Pl[wid][0];
      // S^T = mfma32(K rows, Q rows)
      f32x4 sa[4][2] = {};
      __builtin_amdgcn_s_setprio(1);
#pragma unroll
      for (int kk = 0; kk < 2; ++kk) {
        const int kb = (kk == 0) ? ka0 : ka1;
        s16x8 ka[4];
#pragma unroll
        for (int ki = 0; ki < 4; ++ki)
          ka[ki] = *(const s16x8*)&kl[kb + ki * 1024];
#pragma unroll
        for (int ki = 0; ki < 4; ++ki)
#pragma unroll
          for (int qi = 0; qi < 2; ++qi)
            sa[ki][qi] = __builtin_amdgcn_mfma_f32_16x16x32_bf16(ka[ki], aq[qi][kk], sa[ki][qi], 0, 0, 0);
      }
      __builtin_amdgcn_s_setprio(0);
      if (kv0 + 63 > q0) {                // boundary: causal mask
#pragma unroll
        for (int ki = 0; ki < 4; ++ki)
#pragma unroll
          for (int qi = 0; qi < 2; ++qi)
#pragma unroll
            for (int r = 0; r < 4; ++r) {
              int kvg = kv0 + ki * 16 + l4 * 4 + r;
              int qg = q0 + qi * 16 + l15;
              if (kvg > qg) sa[ki][qi][r] = -INFINITY;
            }
      }
      // P = exp2(S'), packed bf16 pairs
      unsigned pw[4][2][2];
#pragma unroll
      for (int ki = 0; ki < 4; ++ki)
#pragma unroll
        for (int qi = 0; qi < 2; ++qi) {
          float e0 = nexp2(sa[ki][qi][0]);
          float e1 = nexp2(sa[ki][qi][1]);
          float e2 = nexp2(sa[ki][qi][2]);
          float e3 = nexp2(sa[ki][qi][3]);
          pw[ki][qi][0] = pkbf_fast(e0, e1);
          pw[ki][qi][1] = pkbf_fast(e2, e3);
        }
      // per-qi: P round-trip to K=32 layout, then l + PV on mfma32
      __builtin_amdgcn_s_setprio(1);
#pragma unroll
      for (int qi = 0; qi < 2; ++qi) {
#pragma unroll
        for (int ki = 0; ki < 4; ++ki) {
          u32x2 w; w[0] = pw[ki][qi][0]; w[1] = pw[ki][qi][1];
          *(u32x2*)&Pw[pwo[ki]] = w;
        }
        s16x8 pb0 = *(const s16x8*)&Pw[pro0];
        s16x8 pb1 = *(const s16x8*)&Pw[pro1];
        lacc[qi] = __builtin_amdgcn_mfma_f32_16x16x32_bf16(ones8, pb0, lacc[qi], 0, 0, 0);
        lacc[qi] = __builtin_amdgcn_mfma_f32_16x16x32_bf16(ones8, pb1, lacc[qi], 0, 0, 0);
#pragma unroll
        for (int df = 0; df < 4; ++df) {
          s16x8 av0 = *(const s16x8*)&vt[df * 1024 + vro0];
          s16x8 av1 = *(const s16x8*)&vt[df * 1024 + vro1];
          acc_o[df][qi] = __builtin_amdgcn_mfma_f32_16x16x32_bf16(av0, pb0, acc_o[df][qi], 0, 0, 0);
          acc_o[df][qi] = __builtin_amdgcn_mfma_f32_16x16x32_bf16(av1, pb1, acc_o[df][qi], 0, 0, 0);
        }
      }
      __builtin_amdgcn_s_setprio(0);
    }
    cur ^= 1;
  }

  const int b = bh >> 4, h = bh & 15;
  const float ISQC = 2.35482208f;         // 1 / sqrt(0.125 * log2 e)
  float inv[2] = {ISQC / lacc[0][0], ISQC / lacc[1][0]};
#pragma unroll
  for (int df = 0; df < 4; ++df)
#pragma unroll
    for (int qi = 0; qi < 2; ++qi) {
      int qg = q0 + qi * 16 + l15;
      int col = h * 64 + df * 16 + l4 * 4;
      u32x2 pk;
      pk[0] = pkbf_fast(acc_o[df][qi][0] * inv[qi], acc_o[df][qi][1] * inv[qi]);
      pk[1] = pkbf_fast(acc_o[df][qi][2] * inv[qi], acc_o[df][qi][3] * inv[qi]);
      *(u32x2*)&Ctx[(size_t)(b * S_ + qg) * DM_ + col] = pk;
    }
}

extern "C" void kernel_launch(void* const* d_in, const int* in_sizes, int n_in,
                              void* d_out, int out_size, void* d_ws, size_t ws_size,
                              hipStream_t stream) {
  const float* x  = (const float*)d_in[0];
  const float* Wq = (const float*)d_in[1];
  const float* Wo = (const float*)d_in[2];
  const float* bo = (const float*)d_in[3];
  float* out = (float*)d_out;
  char* ws = (char*)d_ws;

  short* xb  = (short*)(ws);                 // 16 MB (x bf16, reused as ctx)
  short* WqT = (short*)(ws + 16777216);      //  2 MB
  short* WoT = (short*)(ws + 18874368);      //  2 MB
  short* Qb  = (short*)(ws + 20971520);      // 16 MB  [bh][s][d], *sqrt(C)
  short* QbT = (short*)(ws + 37748736);      // 16 MB  [bh][d][s], *sqrt(C)
  short* Ctx = xb;  // alias: x dead after GEMM1

  cvt_kernel<<<4096, 256, 0, stream>>>(x, xb);
  tcvt_kernel<<<dim3(32, 32, 2), 256, 0, stream>>>(Wq, Wo, WqT, WoT);
  gemm_kernel<0><<<dim3(8, 64), 256, 0, stream>>>(xb, WqT, Qb, QbT, nullptr);
  attn_kernel<<<1024, 256, 0, stream>>>(Qb, QbT, Ctx);
  gemm_kernel<1><<<dim3(8, 64), 256, 0, stream>>>(Ctx, WoT, out, nullptr, bo);
}

// Round 21
// 116.101 us; speedup vs baseline: 1.0198x; 1.0176x over previous
//
#include <hip/hip_runtime.h>
#include <hip/hip_bf16.h>
#include <math.h>

#define B_ 4
#define S_ 2048
#define NH_ 16
#define DH_ 64
#define DM_ 1024

typedef __attribute__((ext_vector_type(4))) float f32x4;
typedef __attribute__((ext_vector_type(8))) short s16x8;
typedef __attribute__((ext_vector_type(2))) unsigned u32x2;

// native exp2 via device-libs (lowers to v_exp_f32, compiler-managed hazards)
extern "C" __device__ float __ocml_native_exp2_f32(float);
static __device__ __forceinline__ float nexp2(float x) {
  return __ocml_native_exp2_f32(x);
}

static __device__ __forceinline__ short f2bf(float f) {
  union { float f; unsigned u; } c; c.f = f;
  unsigned r = c.u + 0x7fffu + ((c.u >> 16) & 1u);
  return (short)(r >> 16);
}

// single-instruction packed f32->bf16 (RNE), lo = a, hi = b (HW-proven)
static __device__ __forceinline__ unsigned pkbf_fast(float a, float b) {
  unsigned r;
  asm("v_cvt_pk_bf16_f32 %0, %1, %2" : "=v"(r) : "v"(a), "v"(b));
  return r;
}

static __device__ __forceinline__ void gload16(const void* g, void* l) {
  __builtin_amdgcn_global_load_lds(
      (const __attribute__((address_space(1))) void*)g,
      (__attribute__((address_space(3))) void*)l, 16, 0, 0);
}

// ---------- fused pre-pass: x fp32->bf16 (blocks 0..4095) + both W
// transpose+converts (blocks 4096..6143; flattened 32x32x2). Both parts are
// BW-bound; fusing runs them as one wavefront and saves a launch. ----------
__global__ void prep_kernel(const float* __restrict__ in, short* __restrict__ out,
                            const float* __restrict__ W0, const float* __restrict__ W1,
                            short* __restrict__ T0, short* __restrict__ T1) {
  __shared__ float t[32][33];
  if (blockIdx.x < 4096) {
    int i = (blockIdx.x * 256 + threadIdx.x) * 8;
    f32x4 a = *(const f32x4*)(in + i);
    f32x4 b = *(const f32x4*)(in + i + 4);
    s16x8 o;
    o[0] = f2bf(a[0]); o[1] = f2bf(a[1]); o[2] = f2bf(a[2]); o[3] = f2bf(a[3]);
    o[4] = f2bf(b[0]); o[5] = f2bf(b[1]); o[6] = f2bf(b[2]); o[7] = f2bf(b[3]);
    *(s16x8*)(out + i) = o;
  } else {
    int r = blockIdx.x - 4096;
    const float* W = (r >> 10) ? W1 : W0;
    short* WT = (r >> 10) ? T1 : T0;
    int bn = (r & 31) * 32, bk = ((r >> 5) & 31) * 32;
    int tx = threadIdx.x & 31, ty = threadIdx.x >> 5;
#pragma unroll
    for (int rr = 0; rr < 32; rr += 8)
      t[ty + rr][tx] = W[(size_t)(bk + ty + rr) * DM_ + bn + tx];
    __syncthreads();
#pragma unroll
    for (int rr = 0; rr < 32; rr += 8)
      WT[(size_t)(bn + ty + rr) * DM_ + bk + tx] = f2bf(t[tx][ty + rr]);
  }
}

// ---------- bf16 GEMM: 128x128 tiles (proven), grid (8,64).
// EPI0: write Q [bh][s][d] and Q^T [bh][d][s], pre-scaled by sqrt(C).
// EPI1: bias add, fp32 out. ----------
template <int EPI>
__global__ __launch_bounds__(256, 2) void gemm_kernel(
    const short* __restrict__ A, const short* __restrict__ BT,
    void* __restrict__ Cout, short* __restrict__ CoutT,
    const float* __restrict__ bias) {
  __shared__ short Al[128 * 64];
  __shared__ short Bl[128 * 64];
  const int tid = threadIdx.x;
  const int wid = tid >> 6, lane = tid & 63;
  const int l15 = lane & 15, l4 = lane >> 4;
  const int bm = blockIdx.y * 128, bn = blockIdx.x * 128;
  const int wm = (wid >> 1) * 64, wn = (wid & 1) * 64;
  f32x4 acc[4][4] = {};

  for (int kt = 0; kt < DM_; kt += 64) {
    __syncthreads();
#pragma unroll
    for (int j = 0; j < 4; ++j) {
      int s = j * 256 + tid;
      int row = s >> 3;
      int sl = (s & 7) ^ (row & 7);
      gload16(A + (size_t)(bm + row) * DM_ + kt + sl * 8, &Al[j * 2048 + wid * 512]);
    }
#pragma unroll
    for (int j = 0; j < 4; ++j) {
      int s = j * 256 + tid;
      int row = s >> 3;
      int sl = (s & 7) ^ (row & 7);
      gload16(BT + (size_t)(bn + row) * DM_ + kt + sl * 8, &Bl[j * 2048 + wid * 512]);
    }
    __syncthreads();
#pragma unroll
    for (int kk = 0; kk < 2; ++kk) {
      s16x8 af[4], bfr[4];
#pragma unroll
      for (int mi = 0; mi < 4; ++mi) {
        int row = wm + mi * 16 + l15;
        int sl = (kk * 4 + l4) ^ (row & 7);
        af[mi] = *(const s16x8*)&Al[row * 64 + sl * 8];
      }
#pragma unroll
      for (int ni = 0; ni < 4; ++ni) {
        int row = wn + ni * 16 + l15;
        int sl = (kk * 4 + l4) ^ (row & 7);
        bfr[ni] = *(const s16x8*)&Bl[row * 64 + sl * 8];
      }
#pragma unroll
      for (int mi = 0; mi < 4; ++mi)
#pragma unroll
        for (int ni = 0; ni < 4; ++ni)
          acc[mi][ni] = __builtin_amdgcn_mfma_f32_16x16x32_bf16(af[mi], bfr[ni], acc[mi][ni], 0, 0, 0);
    }
  }

  if (EPI == 0) {
    const float sc = 0.42466089786f;     // sqrt(0.125 * log2 e)
    short* Q = (short*)Cout;
#pragma unroll
    for (int mi = 0; mi < 4; ++mi)
#pragma unroll
      for (int ni = 0; ni < 4; ++ni) {
        int rr0 = bm + wm + mi * 16 + l4 * 4;
        int cc = bn + wn + ni * 16 + l15;
        int b = rr0 >> 11, s0 = rr0 & 2047, h = cc >> 6, d = cc & 63;
        int bh = b * NH_ + h;
        u32x2 pk;
        pk[0] = pkbf_fast(acc[mi][ni][0] * sc, acc[mi][ni][1] * sc);
        pk[1] = pkbf_fast(acc[mi][ni][2] * sc, acc[mi][ni][3] * sc);
        Q[(((size_t)bh * S_ + s0 + 0) << 6) + d] = (short)(pk[0] & 0xffff);
        Q[(((size_t)bh * S_ + s0 + 1) << 6) + d] = (short)(pk[0] >> 16);
        Q[(((size_t)bh * S_ + s0 + 2) << 6) + d] = (short)(pk[1] & 0xffff);
        Q[(((size_t)bh * S_ + s0 + 3) << 6) + d] = (short)(pk[1] >> 16);
        *(u32x2*)&CoutT[(((size_t)bh * DH_ + d) << 11) + s0] = pk;
      }
  } else {
    float* O = (float*)Cout;
#pragma unroll
    for (int mi = 0; mi < 4; ++mi)
#pragma unroll
      for (int ni = 0; ni < 4; ++ni)
#pragma unroll
        for (int r = 0; r < 4; ++r) {
          int rr = bm + wm + mi * 16 + l4 * 4 + r;
          int cc = bn + wn + ni * 16 + l15;
          O[(size_t)rr * DM_ + cc] = acc[mi][ni][r] + bias[cc];
        }
  }
}

// ---------- causal flash attention, Q=K=V (inputs pre-scaled by sqrt(C)) ----
// PV and l use K=32 MFMA (16x16x16 costs the SAME cycles as 16x16x32 on
// CDNA4). P re-laid-out for the K=32 B-operand via a 2KB wave-private LDS
// round-trip (XOR-swizzled). Shift-free softmax; exp2 native; cvt_pk packing.
__global__ __launch_bounds__(256, 4) void attn_kernel(
    const short* __restrict__ Qb, const short* __restrict__ QbT,
    short* __restrict__ Ctx) {
  __shared__ short Kl[2][64 * 64];
  __shared__ short Vt[2][64 * 64];
  __shared__ short Pl[4][16 * 64];        // per-wave P buffer (per-qi reuse)
  const int tid = threadIdx.x;
  const int wid = tid >> 6, lane = tid & 63;
  const int l15 = lane & 15, l4 = lane >> 4;
  const int bid = blockIdx.x;
  const int bh = bid & 63;
  const int g = bid >> 6;
  const int qt = (int)((0x32104567ba98cdefULL >> (g * 4)) & 15);
  const short* Qh = Qb + (size_t)bh * S_ * DH_;
  const short* QTh = QbT + (size_t)bh * DH_ * S_;
  const int q0 = qt * 128 + wid * 32;

  s16x8 aq[2][2];
#pragma unroll
  for (int qi = 0; qi < 2; ++qi)
#pragma unroll
    for (int kk = 0; kk < 2; ++kk)
      aq[qi][kk] = *(const s16x8*)(Qh + (size_t)(q0 + qi * 16 + l15) * DH_ + kk * 32 + l4 * 8);

  f32x4 acc_o[4][2] = {};
  f32x4 lacc[2] = {};
  s16x8 ones8;
#pragma unroll
  for (int i = 0; i < 8; ++i) ones8[i] = (short)0x3F80;

  // hoisted LDS offsets (short units)
  const int e7 = l15 & 7;
  const int ka0 = l15 * 64 + ((l4) ^ e7) * 8;
  const int ka1 = l15 * 64 + ((4 + l4) ^ e7) * 8;
  // V^T K=32 A-frag read: octet 4*blk + l4, row df*16+l15 (df*1024 folded)
  const int vro0 = l15 * 64 + ((l4) ^ e7) * 8;        // blk 0
  const int vro1 = l15 * 64 + ((4 + l4) ^ e7) * 8;    // blk 1
  // P write (b64): octet 2ki+(l4>>1), half l4&1
  int pwo[4];
#pragma unroll
  for (int ki = 0; ki < 4; ++ki)
    pwo[ki] = l15 * 64 + (((2 * ki + (l4 >> 1)) ^ e7) << 3) + (l4 & 1) * 4;
  // P read (b128): octet 4*blk + l4 (same swizzle as write)
  const int pro0 = vro0, pro1 = vro1;

  const int c0 = wid * 64 + lane, c1 = c0 + 256;
  const int r0 = c0 >> 3, s0 = (c0 & 7) ^ (r0 & 7);
  const int r1 = c1 >> 3, s1 = (c1 & 7) ^ (r1 & 7);
  const short* pK0 = Qh + r0 * 64 + s0 * 8;
  const short* pK1 = Qh + r1 * 64 + s1 * 8;
  const short* pV0 = QTh + (size_t)r0 * S_ + s0 * 8;
  const short* pV1 = QTh + (size_t)r1 * S_ + s1 * 8;

  auto stage = [&](int buf) {
    gload16(pK0, &Kl[buf][wid * 512]);
    gload16(pK1, &Kl[buf][wid * 512 + 2048]);
    gload16(pV0, &Vt[buf][wid * 512]);
    gload16(pV1, &Vt[buf][wid * 512 + 2048]);
    pK0 += 4096; pK1 += 4096;
    pV0 += 64;   pV1 += 64;
  };

  stage(0);

  int cur = 0;
  const int nt = qt * 2 + 2;
  for (int t = 0; t < nt; ++t) {
    asm volatile("s_waitcnt vmcnt(0)" ::: "memory");
    __syncthreads();
    if (t + 1 < nt) stage(cur ^ 1);
    const int kv0 = t * 64;

    if (kv0 <= q0) {
      const short* kl = &Kl[cur][0];
      const short* vt = &Vt[cur][0];
      short* Pw = &Pl[wid][0];
      // S^T = mfma32(K rows, Q rows)
      f32x4 sa[4][2] = {};
      __builtin_amdgcn_s_setprio(1);
#pragma unroll
      for (int kk = 0; kk < 2; ++kk) {
        const int kb = (kk == 0) ? ka0 : ka1;
        s16x8 ka[4];
#pragma unroll
        for (int ki = 0; ki < 4; ++ki)
          ka[ki] = *(const s16x8*)&kl[kb + ki * 1024];
#pragma unroll
        for (int ki = 0; ki < 4; ++ki)
#pragma unroll
          for (int qi = 0; qi < 2; ++qi)
            sa[ki][qi] = __builtin_amdgcn_mfma_f32_16x16x32_bf16(ka[ki], aq[qi][kk], sa[ki][qi], 0, 0, 0);
      }
      __builtin_amdgcn_s_setprio(0);
      if (kv0 + 63 > q0) {                // boundary: causal mask
#pragma unroll
        for (int ki = 0; ki < 4; ++ki)
#pragma unroll
          for (int qi = 0; qi < 2; ++qi)
#pragma unroll
            for (int r = 0; r < 4; ++r) {
              int kvg = kv0 + ki * 16 + l4 * 4 + r;
              int qg = q0 + qi * 16 + l15;
              if (kvg > qg) sa[ki][qi][r] = -INFINITY;
            }
      }
      // P = exp2(S'), packed bf16 pairs
      unsigned pw[4][2][2];
#pragma unroll
      for (int ki = 0; ki < 4; ++ki)
#pragma unroll
        for (int qi = 0; qi < 2; ++qi) {
          float e0 = nexp2(sa[ki][qi][0]);
          float e1 = nexp2(sa[ki][qi][1]);
          float e2 = nexp2(sa[ki][qi][2]);
          float e3 = nexp2(sa[ki][qi][3]);
          pw[ki][qi][0] = pkbf_fast(e0, e1);
          pw[ki][qi][1] = pkbf_fast(e2, e3);
        }
      // per-qi: P round-trip to K=32 layout, then l + PV on mfma32
      __builtin_amdgcn_s_setprio(1);
#pragma unroll
      for (int qi = 0; qi < 2; ++qi) {
#pragma unroll
        for (int ki = 0; ki < 4; ++ki) {
          u32x2 w; w[0] = pw[ki][qi][0]; w[1] = pw[ki][qi][1];
          *(u32x2*)&Pw[pwo[ki]] = w;
        }
        s16x8 pb0 = *(const s16x8*)&Pw[pro0];
        s16x8 pb1 = *(const s16x8*)&Pw[pro1];
        lacc[qi] = __builtin_amdgcn_mfma_f32_16x16x32_bf16(ones8, pb0, lacc[qi], 0, 0, 0);
        lacc[qi] = __builtin_amdgcn_mfma_f32_16x16x32_bf16(ones8, pb1, lacc[qi], 0, 0, 0);
#pragma unroll
        for (int df = 0; df < 4; ++df) {
          s16x8 av0 = *(const s16x8*)&vt[df * 1024 + vro0];
          s16x8 av1 = *(const s16x8*)&vt[df * 1024 + vro1];
          acc_o[df][qi] = __builtin_amdgcn_mfma_f32_16x16x32_bf16(av0, pb0, acc_o[df][qi], 0, 0, 0);
          acc_o[df][qi] = __builtin_amdgcn_mfma_f32_16x16x32_bf16(av1, pb1, acc_o[df][qi], 0, 0, 0);
        }
      }
      __builtin_amdgcn_s_setprio(0);
    }
    cur ^= 1;
  }

  const int b = bh >> 4, h = bh & 15;
  const float ISQC = 2.35482208f;         // 1 / sqrt(0.125 * log2 e)
  float inv[2] = {ISQC / lacc[0][0], ISQC / lacc[1][0]};
#pragma unroll
  for (int df = 0; df < 4; ++df)
#pragma unroll
    for (int qi = 0; qi < 2; ++qi) {
      int qg = q0 + qi * 16 + l15;
      int col = h * 64 + df * 16 + l4 * 4;
      u32x2 pk;
      pk[0] = pkbf_fast(acc_o[df][qi][0] * inv[qi], acc_o[df][qi][1] * inv[qi]);
      pk[1] = pkbf_fast(acc_o[df][qi][2] * inv[qi], acc_o[df][qi][3] * inv[qi]);
      *(u32x2*)&Ctx[(size_t)(b * S_ + qg) * DM_ + col] = pk;
    }
}

extern "C" void kernel_launch(void* const* d_in, const int* in_sizes, int n_in,
                              void* d_out, int out_size, void* d_ws, size_t ws_size,
                              hipStream_t stream) {
  const float* x  = (const float*)d_in[0];
  const float* Wq = (const float*)d_in[1];
  const float* Wo = (const float*)d_in[2];
  const float* bo = (const float*)d_in[3];
  float* out = (float*)d_out;
  char* ws = (char*)d_ws;

  short* xb  = (short*)(ws);                 // 16 MB (x bf16, reused as ctx)
  short* WqT = (short*)(ws + 16777216);      //  2 MB
  short* WoT = (short*)(ws + 18874368);      //  2 MB
  short* Qb  = (short*)(ws + 20971520);      // 16 MB  [bh][s][d], *sqrt(C)
  short* QbT = (short*)(ws + 37748736);      // 16 MB  [bh][d][s], *sqrt(C)
  short* Ctx = xb;  // alias: x dead after GEMM1

  prep_kernel<<<6144, 256, 0, stream>>>(x, xb, Wq, Wo, WqT, WoT);
  gemm_kernel<0><<<dim3(8, 64), 256, 0, stream>>>(xb, WqT, Qb, QbT, nullptr);
  attn_kernel<<<1024, 256, 0, stream>>>(Qb, QbT, Ctx);
  gemm_kernel<1><<<dim3(8, 64), 256, 0, stream>>>(Ctx, WoT, out, nullptr, bo);
}

// Round 22
// 115.710 us; speedup vs baseline: 1.0233x; 1.0034x over previous
//
#include <hip/hip_runtime.h>
#include <hip/hip_bf16.h>
#include <math.h>

#define B_ 4
#define S_ 2048
#define NH_ 16
#define DH_ 64
#define DM_ 1024

typedef __attribute__((ext_vector_type(4))) float f32x4;
typedef __attribute__((ext_vector_type(8))) short s16x8;
typedef __attribute__((ext_vector_type(2))) unsigned u32x2;

// native exp2 via device-libs (lowers to v_exp_f32, compiler-managed hazards)
extern "C" __device__ float __ocml_native_exp2_f32(float);
static __device__ __forceinline__ float nexp2(float x) {
  return __ocml_native_exp2_f32(x);
}

static __device__ __forceinline__ short f2bf(float f) {
  union { float f; unsigned u; } c; c.f = f;
  unsigned r = c.u + 0x7fffu + ((c.u >> 16) & 1u);
  return (short)(r >> 16);
}

// single-instruction packed f32->bf16 (RNE), lo = a, hi = b (HW-proven)
static __device__ __forceinline__ unsigned pkbf_fast(float a, float b) {
  unsigned r;
  asm("v_cvt_pk_bf16_f32 %0, %1, %2" : "=v"(r) : "v"(a), "v"(b));
  return r;
}

static __device__ __forceinline__ void gload16(const void* g, void* l) {
  __builtin_amdgcn_global_load_lds(
      (const __attribute__((address_space(1))) void*)g,
      (__attribute__((address_space(3))) void*)l, 16, 0, 0);
}

// ---------- fused pre-pass: x fp32->bf16 (blocks 0..4095) + both W
// transpose+converts (blocks 4096..6143; flattened 32x32x2). Both parts are
// BW-bound; fusing runs them as one wavefront and saves a launch. ----------
__global__ void prep_kernel(const float* __restrict__ in, short* __restrict__ out,
                            const float* __restrict__ W0, const float* __restrict__ W1,
                            short* __restrict__ T0, short* __restrict__ T1) {
  __shared__ float t[32][33];
  if (blockIdx.x < 4096) {
    int i = (blockIdx.x * 256 + threadIdx.x) * 8;
    f32x4 a = *(const f32x4*)(in + i);
    f32x4 b = *(const f32x4*)(in + i + 4);
    s16x8 o;
    o[0] = f2bf(a[0]); o[1] = f2bf(a[1]); o[2] = f2bf(a[2]); o[3] = f2bf(a[3]);
    o[4] = f2bf(b[0]); o[5] = f2bf(b[1]); o[6] = f2bf(b[2]); o[7] = f2bf(b[3]);
    *(s16x8*)(out + i) = o;
  } else {
    int r = blockIdx.x - 4096;
    const float* W = (r >> 10) ? W1 : W0;
    short* WT = (r >> 10) ? T1 : T0;
    int bn = (r & 31) * 32, bk = ((r >> 5) & 31) * 32;
    int tx = threadIdx.x & 31, ty = threadIdx.x >> 5;
#pragma unroll
    for (int rr = 0; rr < 32; rr += 8)
      t[ty + rr][tx] = W[(size_t)(bk + ty + rr) * DM_ + bn + tx];
    __syncthreads();
#pragma unroll
    for (int rr = 0; rr < 32; rr += 8)
      WT[(size_t)(bn + ty + rr) * DM_ + bk + tx] = f2bf(t[tx][ty + rr]);
  }
}

// ---------- bf16 GEMM: 128x128 tiles (proven), grid (8,64).
// EPI0: write Q [bh][s][d] and Q^T [bh][d][s], pre-scaled by sqrt(C).
// EPI1: bias add, fp32 out. ----------
template <int EPI>
__global__ __launch_bounds__(256, 2) void gemm_kernel(
    const short* __restrict__ A, const short* __restrict__ BT,
    void* __restrict__ Cout, short* __restrict__ CoutT,
    const float* __restrict__ bias) {
  __shared__ short Al[128 * 64];
  __shared__ short Bl[128 * 64];
  const int tid = threadIdx.x;
  const int wid = tid >> 6, lane = tid & 63;
  const int l15 = lane & 15, l4 = lane >> 4;
  const int bm = blockIdx.y * 128, bn = blockIdx.x * 128;
  const int wm = (wid >> 1) * 64, wn = (wid & 1) * 64;
  f32x4 acc[4][4] = {};

  for (int kt = 0; kt < DM_; kt += 64) {
    __syncthreads();
#pragma unroll
    for (int j = 0; j < 4; ++j) {
      int s = j * 256 + tid;
      int row = s >> 3;
      int sl = (s & 7) ^ (row & 7);
      gload16(A + (size_t)(bm + row) * DM_ + kt + sl * 8, &Al[j * 2048 + wid * 512]);
    }
#pragma unroll
    for (int j = 0; j < 4; ++j) {
      int s = j * 256 + tid;
      int row = s >> 3;
      int sl = (s & 7) ^ (row & 7);
      gload16(BT + (size_t)(bn + row) * DM_ + kt + sl * 8, &Bl[j * 2048 + wid * 512]);
    }
    __syncthreads();
#pragma unroll
    for (int kk = 0; kk < 2; ++kk) {
      s16x8 af[4], bfr[4];
#pragma unroll
      for (int mi = 0; mi < 4; ++mi) {
        int row = wm + mi * 16 + l15;
        int sl = (kk * 4 + l4) ^ (row & 7);
        af[mi] = *(const s16x8*)&Al[row * 64 + sl * 8];
      }
#pragma unroll
      for (int ni = 0; ni < 4; ++ni) {
        int row = wn + ni * 16 + l15;
        int sl = (kk * 4 + l4) ^ (row & 7);
        bfr[ni] = *(const s16x8*)&Bl[row * 64 + sl * 8];
      }
#pragma unroll
      for (int mi = 0; mi < 4; ++mi)
#pragma unroll
        for (int ni = 0; ni < 4; ++ni)
          acc[mi][ni] = __builtin_amdgcn_mfma_f32_16x16x32_bf16(af[mi], bfr[ni], acc[mi][ni], 0, 0, 0);
    }
  }

  if (EPI == 0) {
    const float sc = 0.42466089786f;     // sqrt(0.125 * log2 e)
    short* Q = (short*)Cout;
#pragma unroll
    for (int mi = 0; mi < 4; ++mi)
#pragma unroll
      for (int ni = 0; ni < 4; ++ni) {
        int rr0 = bm + wm + mi * 16 + l4 * 4;
        int cc = bn + wn + ni * 16 + l15;
        int b = rr0 >> 11, s0 = rr0 & 2047, h = cc >> 6, d = cc & 63;
        int bh = b * NH_ + h;
        u32x2 pk;
        pk[0] = pkbf_fast(acc[mi][ni][0] * sc, acc[mi][ni][1] * sc);
        pk[1] = pkbf_fast(acc[mi][ni][2] * sc, acc[mi][ni][3] * sc);
        Q[(((size_t)bh * S_ + s0 + 0) << 6) + d] = (short)(pk[0] & 0xffff);
        Q[(((size_t)bh * S_ + s0 + 1) << 6) + d] = (short)(pk[0] >> 16);
        Q[(((size_t)bh * S_ + s0 + 2) << 6) + d] = (short)(pk[1] & 0xffff);
        Q[(((size_t)bh * S_ + s0 + 3) << 6) + d] = (short)(pk[1] >> 16);
        *(u32x2*)&CoutT[(((size_t)bh * DH_ + d) << 11) + s0] = pk;
      }
  } else {
    float* O = (float*)Cout;
#pragma unroll
    for (int mi = 0; mi < 4; ++mi)
#pragma unroll
      for (int ni = 0; ni < 4; ++ni)
#pragma unroll
        for (int r = 0; r < 4; ++r) {
          int rr = bm + wm + mi * 16 + l4 * 4 + r;
          int cc = bn + wn + ni * 16 + l15;
          O[(size_t)rr * DM_ + cc] = acc[mi][ni][r] + bias[cc];
        }
  }
}

// ---------- causal flash attention, Q=K=V (inputs pre-scaled by sqrt(C)) ----
// PV and l use K=32 MFMA (16x16x16 costs the SAME cycles as 16x16x32 on
// CDNA4). P re-laid-out for the K=32 B-operand via a 2KB wave-private LDS
// round-trip (XOR-swizzled). Shift-free softmax; exp2 native; cvt_pk packing.
__global__ __launch_bounds__(256, 4) void attn_kernel(
    const short* __restrict__ Qb, const short* __restrict__ QbT,
    short* __restrict__ Ctx) {
  __shared__ short Kl[2][64 * 64];
  __shared__ short Vt[2][64 * 64];
  __shared__ short Pl[4][16 * 64];        // per-wave P buffer (per-qi reuse)
  const int tid = threadIdx.x;
  const int wid = tid >> 6, lane = tid & 63;
  const int l15 = lane & 15, l4 = lane >> 4;
  const int bid = blockIdx.x;
  const int bh = bid & 63;
  const int g = bid >> 6;
  const int qt = (int)((0x32104567ba98cdefULL >> (g * 4)) & 15);
  const short* Qh = Qb + (size_t)bh * S_ * DH_;
  const short* QTh = QbT + (size_t)bh * DH_ * S_;
  const int q0 = qt * 128 + wid * 32;

  s16x8 aq[2][2];
#pragma unroll
  for (int qi = 0; qi < 2; ++qi)
#pragma unroll
    for (int kk = 0; kk < 2; ++kk)
      aq[qi][kk] = *(const s16x8*)(Qh + (size_t)(q0 + qi * 16 + l15) * DH_ + kk * 32 + l4 * 8);

  f32x4 acc_o[4][2] = {};
  f32x4 lacc[2] = {};
  s16x8 ones8;
#pragma unroll
  for (int i = 0; i < 8; ++i) ones8[i] = (short)0x3F80;

  // hoisted LDS offsets (short units)
  const int e7 = l15 & 7;
  const int ka0 = l15 * 64 + ((l4) ^ e7) * 8;
  const int ka1 = l15 * 64 + ((4 + l4) ^ e7) * 8;
  // V^T K=32 A-frag read: octet 4*blk + l4, row df*16+l15 (df*1024 folded)
  const int vro0 = l15 * 64 + ((l4) ^ e7) * 8;        // blk 0
  const int vro1 = l15 * 64 + ((4 + l4) ^ e7) * 8;    // blk 1
  // P write (b64): octet 2ki+(l4>>1), half l4&1
  int pwo[4];
#pragma unroll
  for (int ki = 0; ki < 4; ++ki)
    pwo[ki] = l15 * 64 + (((2 * ki + (l4 >> 1)) ^ e7) << 3) + (l4 & 1) * 4;
  // P read (b128): octet 4*blk + l4 (same swizzle as write)
  const int pro0 = vro0, pro1 = vro1;

  const int c0 = wid * 64 + lane, c1 = c0 + 256;
  const int r0 = c0 >> 3, s0 = (c0 & 7) ^ (r0 & 7);
  const int r1 = c1 >> 3, s1 = (c1 & 7) ^ (r1 & 7);
  const short* pK0 = Qh + r0 * 64 + s0 * 8;
  const short* pK1 = Qh + r1 * 64 + s1 * 8;
  const short* pV0 = QTh + (size_t)r0 * S_ + s0 * 8;
  const short* pV1 = QTh + (size_t)r1 * S_ + s1 * 8;

  auto stage = [&](int buf) {
    gload16(pK0, &Kl[buf][wid * 512]);
    gload16(pK1, &Kl[buf][wid * 512 + 2048]);
    gload16(pV0, &Vt[buf][wid * 512]);
    gload16(pV1, &Vt[buf][wid * 512 + 2048]);
    pK0 += 4096; pK1 += 4096;
    pV0 += 64;   pV1 += 64;
  };

  stage(0);

  int cur = 0;
  const int nt = qt * 2 + 2;
  for (int t = 0; t < nt; ++t) {
    asm volatile("s_waitcnt vmcnt(0)" ::: "memory");
    __syncthreads();
    if (t + 1 < nt) stage(cur ^ 1);
    const int kv0 = t * 64;

    if (kv0 <= q0) {
      const short* kl = &Kl[cur][0];
      const short* vt = &Vt[cur][0];
      short* Pw = &Pl[wid][0];
      // S^T = mfma32(K rows, Q rows)
      f32x4 sa[4][2] = {};
      __builtin_amdgcn_s_setprio(1);
#pragma unroll
      for (int kk = 0; kk < 2; ++kk) {
        const int kb = (kk == 0) ? ka0 : ka1;
        s16x8 ka[4];
#pragma unroll
        for (int ki = 0; ki < 4; ++ki)
          ka[ki] = *(const s16x8*)&kl[kb + ki * 1024];
#pragma unroll
        for (int ki = 0; ki < 4; ++ki)
#pragma unroll
          for (int qi = 0; qi < 2; ++qi)
            sa[ki][qi] = __builtin_amdgcn_mfma_f32_16x16x32_bf16(ka[ki], aq[qi][kk], sa[ki][qi], 0, 0, 0);
      }
      __builtin_amdgcn_s_setprio(0);
      if (kv0 + 63 > q0) {                // boundary: causal mask
#pragma unroll
        for (int ki = 0; ki < 4; ++ki)
#pragma unroll
          for (int qi = 0; qi < 2; ++qi)
#pragma unroll
            for (int r = 0; r < 4; ++r) {
              int kvg = kv0 + ki * 16 + l4 * 4 + r;
              int qg = q0 + qi * 16 + l15;
              if (kvg > qg) sa[ki][qi][r] = -INFINITY;
            }
      }
      // P = exp2(S'), packed bf16 pairs
      unsigned pw[4][2][2];
#pragma unroll
      for (int ki = 0; ki < 4; ++ki)
#pragma unroll
        for (int qi = 0; qi < 2; ++qi) {
          float e0 = nexp2(sa[ki][qi][0]);
          float e1 = nexp2(sa[ki][qi][1]);
          float e2 = nexp2(sa[ki][qi][2]);
          float e3 = nexp2(sa[ki][qi][3]);
          pw[ki][qi][0] = pkbf_fast(e0, e1);
          pw[ki][qi][1] = pkbf_fast(e2, e3);
        }
      // per-qi: P round-trip to K=32 layout, then l + PV on mfma32
      __builtin_amdgcn_s_setprio(1);
#pragma unroll
      for (int qi = 0; qi < 2; ++qi) {
#pragma unroll
        for (int ki = 0; ki < 4; ++ki) {
          u32x2 w; w[0] = pw[ki][qi][0]; w[1] = pw[ki][qi][1];
          *(u32x2*)&Pw[pwo[ki]] = w;
        }
        s16x8 pb0 = *(const s16x8*)&Pw[pro0];
        s16x8 pb1 = *(const s16x8*)&Pw[pro1];
        lacc[qi] = __builtin_amdgcn_mfma_f32_16x16x32_bf16(ones8, pb0, lacc[qi], 0, 0, 0);
        lacc[qi] = __builtin_amdgcn_mfma_f32_16x16x32_bf16(ones8, pb1, lacc[qi], 0, 0, 0);
#pragma unroll
        for (int df = 0; df < 4; ++df) {
          s16x8 av0 = *(const s16x8*)&vt[df * 1024 + vro0];
          s16x8 av1 = *(const s16x8*)&vt[df * 1024 + vro1];
          acc_o[df][qi] = __builtin_amdgcn_mfma_f32_16x16x32_bf16(av0, pb0, acc_o[df][qi], 0, 0, 0);
          acc_o[df][qi] = __builtin_amdgcn_mfma_f32_16x16x32_bf16(av1, pb1, acc_o[df][qi], 0, 0, 0);
        }
      }
      __builtin_amdgcn_s_setprio(0);
    }
    cur ^= 1;
  }

  const int b = bh >> 4, h = bh & 15;
  const float ISQC = 2.35482208f;         // 1 / sqrt(0.125 * log2 e)
  float inv[2] = {ISQC / lacc[0][0], ISQC / lacc[1][0]};
#pragma unroll
  for (int df = 0; df < 4; ++df)
#pragma unroll
    for (int qi = 0; qi < 2; ++qi) {
      int qg = q0 + qi * 16 + l15;
      int col = h * 64 + df * 16 + l4 * 4;
      u32x2 pk;
      pk[0] = pkbf_fast(acc_o[df][qi][0] * inv[qi], acc_o[df][qi][1] * inv[qi]);
      pk[1] = pkbf_fast(acc_o[df][qi][2] * inv[qi], acc_o[df][qi][3] * inv[qi]);
      *(u32x2*)&Ctx[(size_t)(b * S_ + qg) * DM_ + col] = pk;
    }
}

extern "C" void kernel_launch(void* const* d_in, const int* in_sizes, int n_in,
                              void* d_out, int out_size, void* d_ws, size_t ws_size,
                              hipStream_t stream) {
  const float* x  = (const float*)d_in[0];
  const float* Wq = (const float*)d_in[1];
  const float* Wo = (const float*)d_in[2];
  const float* bo = (const float*)d_in[3];
  float* out = (float*)d_out;
  char* ws = (char*)d_ws;

  short* xb  = (short*)(ws);                 // 16 MB (x bf16, reused as ctx)
  short* WqT = (short*)(ws + 16777216);      //  2 MB
  short* WoT = (short*)(ws + 18874368);      //  2 MB
  short* Qb  = (short*)(ws + 20971520);      // 16 MB  [bh][s][d], *sqrt(C)
  short* QbT = (short*)(ws + 37748736);      // 16 MB  [bh][d][s], *sqrt(C)
  short* Ctx = xb;  // alias: x dead after GEMM1

  prep_kernel<<<6144, 256, 0, stream>>>(x, xb, Wq, Wo, WqT, WoT);
  gemm_kernel<0><<<dim3(8, 64), 256, 0, stream>>>(xb, WqT, Qb, QbT, nullptr);
  attn_kernel<<<1024, 256, 0, stream>>>(Qb, QbT, Ctx);
  gemm_kernel<1><<<dim3(8, 64), 256, 0, stream>>>(Ctx, WoT, out, nullptr, bo);
}